// Round 1
// baseline (1256.879 us; speedup 1.0000x reference)
//
#include <hip/hip_runtime.h>

// Com2Net wavefront kernel.
// Dependency: cell (t,i) needs (t,i-1).out2 and (t-1,i+1).out1 -> schedule by
// s = 2t + i; both deps are at s-1. One wave per run, lane j owns agents
// {2j, 2j+1}. Macro-step u: even phase = agent 2j at t=u-j, odd phase =
// agent 2j+1 at same t. Cross-lane comm = shfl by 1 within the wave.

#define T_STEPS 1024
#define N_AGENTS 128

__device__ __forceinline__ float tanh_fast(float x) {
    // tanh(x) = 1 - 2/(1 + exp2(2*log2(e)*x)); exact at +-inf, ~1e-6 abs err.
    float t = __builtin_amdgcn_exp2f(x * 2.8853900817779268f);
    float r = __builtin_amdgcn_rcpf(t + 1.0f);
    return __builtin_fmaf(-2.0f, r, 1.0f);
}

__global__ void __launch_bounds__(64, 1)
com2net_wavefront(const float* __restrict__ runs,
                  const float* __restrict__ W1, const float* __restrict__ b1,
                  const float* __restrict__ W2, const float* __restrict__ b2,
                  float* __restrict__ out)
{
    const int r = blockIdx.x;   // run index
    const int j = threadIdx.x;  // lane 0..63, owns agents 2j and 2j+1

    // Weights are wave-uniform; loads should scalarize to s_load (verify in disasm).
    float w1[10][4], bb1[10], w2[3][10], bb2[3];
#pragma unroll
    for (int k = 0; k < 10; ++k) {
        bb1[k] = b1[k];
#pragma unroll
        for (int c = 0; c < 4; ++c) w1[k][c] = W1[k * 4 + c];
    }
#pragma unroll
    for (int o = 0; o < 3; ++o) {
        bb2[o] = b2[o];
#pragma unroll
        for (int k = 0; k < 10; ++k) w2[o][k] = W2[o * 10 + k];
    }

    // Lane j's input quad for row t: runs[r][t][2j][0..1] ++ runs[r][t][2j+1][0..1]
    const float4* __restrict__ xp =
        (const float4*)(runs + (size_t)r * T_STEPS * N_AGENTS * 2) + j;
    // Lane j's output pair for row t: out[r][t][2j..2j+1]
    float2* __restrict__ op =
        (float2*)(out + (size_t)r * T_STEPS * N_AGENTS) + j;

    // c1*/c2* = out1/out2 of the lane's even/odd agent from its latest timestep.
    // Zero-init == initial comm state; inactive lanes never update, which
    // supplies the comm[0]/comm[2N+1]==0 and t<0 boundary values for free.
    float c1e = 0.f, c2e = 0.f, c1o = 0.f, c2o = 0.f;

    for (int u = 0; u < T_STEPS + 63; ++u) {
        const int t = u - j;
        const bool active = (t >= 0) && (t < T_STEPS);

        float x0 = 0.f, x1 = 0.f, x2 = 0.f, x3 = 0.f;
        if (active) {
            float4 x = *xp;
            x0 = x.x; x1 = x.y; x2 = x.z; x3 = x.w;
        }

        // ---- even phase: agent i = 2j at time t ----
        // comm[4j]   = out2 of agent 2j-1 at t   -> lane j-1's c2o (prev macro-step)
        // comm[4j+3] = out1 of agent 2j+1 at t-1 -> own c1o (prev macro-step)
        float c2p = __shfl_up(c2o, 1);
        if (j == 0) c2p = 0.f;           // comm[0] is never written
        float o0e, o1e, o2e;
        {
            float h[10];
#pragma unroll
            for (int k = 0; k < 10; ++k) {
                float a = bb1[k];
                a = __builtin_fmaf(w1[k][0], x0,  a);
                a = __builtin_fmaf(w1[k][1], x1,  a);
                a = __builtin_fmaf(w1[k][2], c2p, a);
                a = __builtin_fmaf(w1[k][3], c1o, a);
                h[k] = tanh_fast(a);
            }
            o0e = bb2[0]; o1e = bb2[1]; o2e = bb2[2];
#pragma unroll
            for (int k = 0; k < 10; ++k) {
                o0e = __builtin_fmaf(w2[0][k], h[k], o0e);
                o1e = __builtin_fmaf(w2[1][k], h[k], o1e);
                o2e = __builtin_fmaf(w2[2][k], h[k], o2e);
            }
        }
        if (active) { c1e = o1e; c2e = o2e; }

        // ---- odd phase: agent i = 2j+1 at time t ----
        // comm[4j+2] = out2 of agent 2j at t     -> own c2e (just computed)
        // comm[4j+5] = out1 of agent 2j+2 at t-1 -> lane j+1's c1e (its even
        //              phase THIS macro-step ran at t-1)
        float c1p = __shfl_down(c1e, 1);
        if (j == 63) c1p = 0.f;          // comm[2N+1] is never written
        float o0o, o1o, o2o;
        {
            float h[10];
#pragma unroll
            for (int k = 0; k < 10; ++k) {
                float a = bb1[k];
                a = __builtin_fmaf(w1[k][0], x2,  a);
                a = __builtin_fmaf(w1[k][1], x3,  a);
                a = __builtin_fmaf(w1[k][2], c2e, a);
                a = __builtin_fmaf(w1[k][3], c1p, a);
                h[k] = tanh_fast(a);
            }
            o0o = bb2[0]; o1o = bb2[1]; o2o = bb2[2];
#pragma unroll
            for (int k = 0; k < 10; ++k) {
                o0o = __builtin_fmaf(w2[0][k], h[k], o0o);
                o1o = __builtin_fmaf(w2[1][k], h[k], o1o);
                o2o = __builtin_fmaf(w2[2][k], h[k], o2o);
            }
        }
        if (active) {
            c1o = o1o; c2o = o2o;
            *op = make_float2(o0e, o0o);
            xp += N_AGENTS / 2;   // advance one t-row (64 float4)
            op += N_AGENTS / 2;   // advance one t-row (64 float2)
        }
    }
}

extern "C" void kernel_launch(void* const* d_in, const int* in_sizes, int n_in,
                              void* d_out, int out_size, void* d_ws, size_t ws_size,
                              hipStream_t stream) {
    const float* runs = (const float*)d_in[0];
    const float* W1   = (const float*)d_in[1];
    const float* b1   = (const float*)d_in[2];
    const float* W2   = (const float*)d_in[3];
    const float* b2   = (const float*)d_in[4];
    float* out = (float*)d_out;

    const int R = 128;
    com2net_wavefront<<<R, 64, 0, stream>>>(runs, W1, b1, W2, b2, out);
}

// Round 2
// 807.582 us; speedup vs baseline: 1.5563x; 1.5563x over previous
//
#include <hip/hip_runtime.h>

// Com2Net wavefront kernel, round 2.
// Schedule s = 2t + i; one wave per run, lane j owns agents {2j, 2j+1}.
// R=128 waves run concurrently -> total time == one wave's serial loop, so
// everything here targets the per-macro-step critical path:
//   - input row prefetched one full step ahead (unconditional, clamped index)
//   - v_pk_fma_f32 packing: hidden units paired (2p,2p+1), outputs (o1,o2) paired
//   - dot products tree-reduced (2 chains of 5); shfl operand consumed last

#define T_STEPS 1024
#define N_AGENTS 128

typedef float v2f __attribute__((ext_vector_type(2)));

__device__ __forceinline__ float tanh_fast(float x) {
    // tanh(x) = 1 - 2/(1 + exp2(2*log2(e)*x)); exact at +-inf, ~1e-6 abs err.
    float t = __builtin_amdgcn_exp2f(x * 2.8853900817779268f);
    float r = __builtin_amdgcn_rcpf(t + 1.0f);
    return __builtin_fmaf(-2.0f, r, 1.0f);
}

__device__ __forceinline__ v2f sp(float x) { return (v2f){x, x}; }

// One S2Net eval: inp = [xa, xb, cA, cB] (cA = comm[2i], cB = comm[2i+3]).
// cA is the latest-arriving operand in the even phase (shfl result) is passed
// so that it is consumed by the LAST fma of the preact chain.
#define MLP_EVAL(xa, xb, cA, cB, o0, o12)                                      \
    {                                                                          \
        v2f pre[5];                                                            \
        _Pragma("unroll") for (int p = 0; p < 5; ++p) {                        \
            v2f a = __builtin_elementwise_fma(w1c[0][p], sp(xa), b1p[p]);      \
            a = __builtin_elementwise_fma(w1c[1][p], sp(xb), a);               \
            a = __builtin_elementwise_fma(w1c[3][p], sp(cB), a);               \
            pre[p] = __builtin_elementwise_fma(w1c[2][p], sp(cA), a);          \
        }                                                                      \
        float h[10];                                                           \
        _Pragma("unroll") for (int p = 0; p < 5; ++p) {                        \
            h[2 * p]     = tanh_fast(pre[p].x);                                \
            h[2 * p + 1] = tanh_fast(pre[p].y);                                \
        }                                                                      \
        /* o12 = (out1, out2): the recurrence-critical outputs, tree-reduced */\
        v2f accA = __builtin_elementwise_fma(w2p[0], sp(h[0]), b2p12);         \
        v2f accB = w2p[1] * sp(h[1]);                                          \
        _Pragma("unroll") for (int k = 2; k < 10; k += 2) {                    \
            accA = __builtin_elementwise_fma(w2p[k], sp(h[k]), accA);          \
            accB = __builtin_elementwise_fma(w2p[k + 1], sp(h[k + 1]), accB);  \
        }                                                                      \
        o12 = accA + accB;                                                     \
        /* o0: output-only (not on the recurrence), can lag */                 \
        float s0 = __builtin_fmaf(w2r0[0], h[0], bb2_0);                       \
        float s1 = w2r0[1] * h[1];                                             \
        _Pragma("unroll") for (int k = 2; k < 10; k += 2) {                    \
            s0 = __builtin_fmaf(w2r0[k], h[k], s0);                            \
            s1 = __builtin_fmaf(w2r0[k + 1], h[k + 1], s1);                    \
        }                                                                      \
        o0 = s0 + s1;                                                          \
    }

__global__ void __launch_bounds__(64, 1)
com2net_wavefront(const float* __restrict__ runs,
                  const float* __restrict__ W1, const float* __restrict__ b1,
                  const float* __restrict__ W2, const float* __restrict__ b2,
                  float* __restrict__ out)
{
    const int r = blockIdx.x;   // run index
    const int j = threadIdx.x;  // lane 0..63, owns agents 2j and 2j+1

    // Packed wave-uniform weights (should land in SGPRs).
    v2f w1c[4][5];   // w1c[c][p] = (W1[2p][c], W1[2p+1][c])
    v2f b1p[5];      // (b1[2p], b1[2p+1])
    v2f w2p[10];     // (W2[1][k], W2[2][k])
    float w2r0[10];  // W2[0][k]
#pragma unroll
    for (int p = 0; p < 5; ++p) {
        b1p[p] = (v2f){b1[2 * p], b1[2 * p + 1]};
#pragma unroll
        for (int c = 0; c < 4; ++c)
            w1c[c][p] = (v2f){W1[(2 * p) * 4 + c], W1[(2 * p + 1) * 4 + c]};
    }
#pragma unroll
    for (int k = 0; k < 10; ++k) {
        w2p[k] = (v2f){W2[10 + k], W2[20 + k]};
        w2r0[k] = W2[k];
    }
    const float bb2_0 = b2[0];
    const v2f b2p12 = (v2f){b2[1], b2[2]};

    // Row t, lane j: xbase[t*64 + j] (float4), obase[t*64 + j] (float2).
    const float4* __restrict__ xbase =
        (const float4*)(runs + (size_t)r * T_STEPS * N_AGENTS * 2);
    float2* __restrict__ obase =
        (float2*)(out + (size_t)r * T_STEPS * N_AGENTS);

    // c1*/c2* = out1/out2 of this lane's even/odd agent at its latest t.
    // Zero-init == initial comm; inactive lanes never update -> boundary zeros.
    float c1e = 0.f, c2e = 0.f, c1o = 0.f, c2o = 0.f;

    // Prefetch row for u=0 (clamped index; inactive lanes read garbage rows,
    // whose results are discarded by the select on the state update).
    {
        int t0 = -j;
        int tc = t0 < 0 ? 0 : t0;
        // fallthrough into loop-carried x_next
    }
    int tp = (0 - j) < 0 ? 0 : (0 - j);
    float4 x_next = xbase[(size_t)tp * (N_AGENTS / 2) + j];

#pragma unroll 2
    for (int u = 0; u < T_STEPS + 63; ++u) {
        const int t = u - j;
        const bool active = (t >= 0) && (t < T_STEPS);

        const float4 x = x_next;
        // Prefetch next row now; consumed next iteration.
        int tn = u + 1 - j;
        int tcn = tn < 0 ? 0 : (tn > T_STEPS - 1 ? T_STEPS - 1 : tn);
        x_next = xbase[(size_t)tcn * (N_AGENTS / 2) + j];

        // ---- even phase: agent 2j at t ----
        // comm[4j]   = lane j-1's c2o (prev step);  comm[4j+3] = own c1o.
        float c2pv = __shfl_up(c2o, 1);
        if (j == 0) c2pv = 0.f;  // comm[0] never written
        float o0e; v2f o12e;
        MLP_EVAL(x.x, x.y, c2pv, c1o, o0e, o12e);
        c1e = active ? o12e.x : c1e;
        c2e = active ? o12e.y : c2e;

        // ---- odd phase: agent 2j+1 at t ----
        // comm[4j+2] = own c2e (just computed); comm[4j+5] = lane j+1's c1e.
        float c1pv = __shfl_down(c1e, 1);
        if (j == 63) c1pv = 0.f;  // comm[2N+1] never written
        float o0o; v2f o12o;
        MLP_EVAL(x.z, x.w, c2e, c1pv, o0o, o12o);
        c1o = active ? o12o.x : c1o;
        c2o = active ? o12o.y : c2o;

        if (active) obase[(size_t)t * (N_AGENTS / 2) + j] = make_float2(o0e, o0o);
    }
}

extern "C" void kernel_launch(void* const* d_in, const int* in_sizes, int n_in,
                              void* d_out, int out_size, void* d_ws, size_t ws_size,
                              hipStream_t stream) {
    const float* runs = (const float*)d_in[0];
    const float* W1   = (const float*)d_in[1];
    const float* b1   = (const float*)d_in[2];
    const float* W2   = (const float*)d_in[3];
    const float* b2   = (const float*)d_in[4];
    float* out = (float*)d_out;

    const int R = 128;
    com2net_wavefront<<<R, 64, 0, stream>>>(runs, W1, b1, W2, b2, out);
}

// Round 3
// 572.014 us; speedup vs baseline: 2.1973x; 1.4118x over previous
//
#include <hip/hip_runtime.h>

// Com2Net wavefront kernel, round 3.
// Schedule s = 2t + i; one wave per run, lane j owns agents {2j, 2j+1}.
// R=128 waves run concurrently -> total time == one wave's serial macro-step
// loop (1088 steps). This round targets the two stalls found in R2's
// post-mortem (VALUBusy 8.2% vs 12.5% structural cap, HBM 2.5%):
//   - distance-4 register prefetch (unroll-by-4): 4 row loads in flight,
//     ~1400 cyc consume gap > ~900 cyc HBM latency (m126)
//   - DPP wave_shr1/wave_shl1 replace ds_bpermute shuffles; bound_ctrl
//     zeroes lane 0 / lane 63 = comm[0]/comm[2N+1] boundary for free
//   - tanh scale folded into W1/b1; tanh glue + output dots fully packed
//     (v_pk_fma_f32), horizontal add per output

#define T_STEPS 1024
#define N_AGENTS 128

typedef float v2f __attribute__((ext_vector_type(2)));

__device__ __forceinline__ v2f sp(float x) { return (v2f){x, x}; }

// Whole-wave shift-by-1 via DPP. wave_shr1 (0x138): lane i <- lane i-1,
// lane 0 <- 0 (bound_ctrl). wave_shl1 (0x130): lane i <- lane i+1, lane 63 <- 0.
__device__ __forceinline__ float wave_shr1(float x) {
    int r = __builtin_amdgcn_update_dpp(0, __builtin_bit_cast(int, x),
                                        0x138, 0xF, 0xF, true);
    return __builtin_bit_cast(float, r);
}
__device__ __forceinline__ float wave_shl1(float x) {
    int r = __builtin_amdgcn_update_dpp(0, __builtin_bit_cast(int, x),
                                        0x130, 0xF, 0xF, true);
    return __builtin_bit_cast(float, r);
}

struct Weights {
    v2f w1[4][5];            // w1[c][p] = (W1[2p][c], W1[2p+1][c]) * 2*log2(e)
    v2f b1[5];               // (b1[2p], b1[2p+1]) * 2*log2(e)
    v2f w20[5], w21[5], w22[5];  // W2 row r packed over hidden pairs
    float b20, b21, b22;
};

// One S2Net eval: inp = [xa, xb, cA, cB] with cA = comm[2i], cB = comm[2i+3].
// cA/cB are the recurrence-late operands -> consumed by the last preact fmas.
__device__ __forceinline__ void mlp_eval(const Weights& w, float xa, float xb,
                                         float cA, float cB,
                                         float& o0, float& o1, float& o2) {
    v2f h[5];
#pragma unroll
    for (int p = 0; p < 5; ++p) {
        v2f a = __builtin_elementwise_fma(w.w1[0][p], sp(xa), w.b1[p]);
        a = __builtin_elementwise_fma(w.w1[1][p], sp(xb), a);
        a = __builtin_elementwise_fma(w.w1[3][p], sp(cB), a);
        a = __builtin_elementwise_fma(w.w1[2][p], sp(cA), a);
        // tanh(y) = 1 - 2/(1 + exp2(y*2*log2 e)); scale pre-folded into w1/b1.
        v2f t;
        t.x = __builtin_amdgcn_exp2f(a.x);
        t.y = __builtin_amdgcn_exp2f(a.y);
        t = t + (v2f){1.f, 1.f};
        v2f r;
        r.x = __builtin_amdgcn_rcpf(t.x);
        r.y = __builtin_amdgcn_rcpf(t.y);
        h[p] = __builtin_elementwise_fma((v2f){-2.f, -2.f}, r, (v2f){1.f, 1.f});
    }
    // Output dots packed over hidden dim; horizontal add folds the pair.
    v2f a0 = __builtin_elementwise_fma(w.w20[0], h[0], (v2f){w.b20, 0.f});
    v2f a1 = __builtin_elementwise_fma(w.w21[0], h[0], (v2f){w.b21, 0.f});
    v2f a2 = __builtin_elementwise_fma(w.w22[0], h[0], (v2f){w.b22, 0.f});
#pragma unroll
    for (int p = 1; p < 5; ++p) {
        a0 = __builtin_elementwise_fma(w.w20[p], h[p], a0);
        a1 = __builtin_elementwise_fma(w.w21[p], h[p], a1);
        a2 = __builtin_elementwise_fma(w.w22[p], h[p], a2);
    }
    o0 = a0.x + a0.y;
    o1 = a1.x + a1.y;
    o2 = a2.x + a2.y;
}

__global__ void __launch_bounds__(64, 1)
com2net_wavefront(const float* __restrict__ runs,
                  const float* __restrict__ W1, const float* __restrict__ b1,
                  const float* __restrict__ W2, const float* __restrict__ b2,
                  float* __restrict__ out)
{
    const int r = blockIdx.x;   // run index
    const int j = threadIdx.x;  // lane 0..63, owns agents 2j and 2j+1

    const float S = 2.8853900817779268f;  // 2*log2(e), folded into layer 1
    Weights w;
#pragma unroll
    for (int p = 0; p < 5; ++p) {
        w.b1[p] = (v2f){b1[2 * p] * S, b1[2 * p + 1] * S};
#pragma unroll
        for (int c = 0; c < 4; ++c)
            w.w1[c][p] = (v2f){W1[(2 * p) * 4 + c] * S, W1[(2 * p + 1) * 4 + c] * S};
        w.w20[p] = (v2f){W2[0 * 10 + 2 * p], W2[0 * 10 + 2 * p + 1]};
        w.w21[p] = (v2f){W2[1 * 10 + 2 * p], W2[1 * 10 + 2 * p + 1]};
        w.w22[p] = (v2f){W2[2 * 10 + 2 * p], W2[2 * 10 + 2 * p + 1]};
    }
    w.b20 = b2[0]; w.b21 = b2[1]; w.b22 = b2[2];

    const float4* __restrict__ xbase =
        (const float4*)(runs + (size_t)r * T_STEPS * N_AGENTS * 2);
    float2* __restrict__ obase =
        (float2*)(out + (size_t)r * T_STEPS * N_AGENTS);

    // c1*/c2* = out1/out2 of this lane's even/odd agent at its latest t.
    // Zero-init == initial comm; inactive lanes never update -> t<0 boundary.
    float c1e = 0.f, c2e = 0.f, c1o = 0.f, c2o = 0.f;

    // Clamped row load (OOB lanes re-read row 0/1023; results are discarded
    // by the activity selects, loads hit cache).
    auto ldrow = [&](int t) -> float4 {
        int tc = t < 0 ? 0 : (t > T_STEPS - 1 ? T_STEPS - 1 : t);
        return xbase[tc * (N_AGENTS / 2) + j];
    };

    auto step = [&](int u, const float4& x) {
        const int t = u - j;
        const bool active = (unsigned)t < (unsigned)T_STEPS;

        // ---- even phase: agent 2j at t ----
        // comm[4j]   = lane j-1's c2o (prev macro-step) -> wave_shr1
        // comm[4j+3] = own c1o (prev macro-step)
        float c2pv = wave_shr1(c2o);
        float o0e, o1e, o2e;
        mlp_eval(w, x.x, x.y, c2pv, c1o, o0e, o1e, o2e);
        c1e = active ? o1e : c1e;
        c2e = active ? o2e : c2e;

        // ---- odd phase: agent 2j+1 at t ----
        // comm[4j+2] = own c2e (just computed)
        // comm[4j+5] = lane j+1's c1e (its even phase this step ran at t-1)
        float c1pv = wave_shl1(c1e);
        float o0o, o1o, o2o;
        mlp_eval(w, x.z, x.w, c2e, c1pv, o0o, o1o, o2o);
        c1o = active ? o1o : c1o;
        c2o = active ? o2o : c2o;

        if (active) obase[t * (N_AGENTS / 2) + j] = make_float2(o0e, o0o);
    };

    // Distance-4 register prefetch pipeline, manual unroll-by-4.
    float4 X0 = ldrow(0 - j);
    float4 X1 = ldrow(1 - j);
    float4 X2 = ldrow(2 - j);
    float4 X3 = ldrow(3 - j);

    for (int u = 0; u < T_STEPS + 64; u += 4) {   // 1088 = 4*272 iters
        step(u + 0, X0); X0 = ldrow(u + 4 - j);
        step(u + 1, X1); X1 = ldrow(u + 5 - j);
        step(u + 2, X2); X2 = ldrow(u + 6 - j);
        step(u + 3, X3); X3 = ldrow(u + 7 - j);
    }
}

extern "C" void kernel_launch(void* const* d_in, const int* in_sizes, int n_in,
                              void* d_out, int out_size, void* d_ws, size_t ws_size,
                              hipStream_t stream) {
    const float* runs = (const float*)d_in[0];
    const float* W1   = (const float*)d_in[1];
    const float* b1   = (const float*)d_in[2];
    const float* W2   = (const float*)d_in[3];
    const float* b2   = (const float*)d_in[4];
    float* out = (float*)d_out;

    const int R = 128;
    com2net_wavefront<<<R, 64, 0, stream>>>(runs, W1, b1, W2, b2, out);
}